// Round 7
// baseline (24472.342 us; speedup 1.0000x reference)
//
#include <hip/hip_runtime.h>
#include <hip/hip_bf16.h>
#include <hip/hip_fp16.h>

#define Bb 256
#define Ll 1024
#define Ff 64
#define Ee 128
#define Hh 128

__device__ __forceinline__ float fast_tanh(float x) {
  float e = __expf(2.0f * x);
  return 1.0f - 2.0f / (e + 1.0f);
}
__device__ __forceinline__ float fast_sigmoid(float x) {
  return 1.0f / (1.0f + __expf(-x));
}
// sum over the 4 K-slice lanes {jj, jj+16, jj+32, jj+48}
__device__ __forceinline__ float redu4(float v) {
  v += __shfl_xor(v, 16);
  v += __shfl_xor(v, 32);
  return v;
}
// full 64-lane sum
__device__ __forceinline__ float redu64(float v) {
#pragma unroll
  for (int o = 1; o < 64; o <<= 1) v += __shfl_xor(v, o);
  return v;
}

// Fully fused: one WG per batch row, zero workspace. OUTPUT IS FLOAT32.
// Thread (j = wave*16 + lane&15, ks = lane>>4) owns output row j, K-slice ks.
__global__ __launch_bounds__(512, 2) void k_fused(
    const float* __restrict__ x, const float* __restrict__ dtp,
    const int* __restrict__ mask,
    const float* __restrict__ Wx, const float* __restrict__ bx,
    const float* __restrict__ W1, const float* __restrict__ b1,
    const float* __restrict__ W2, const float* __restrict__ b2,
    const float* __restrict__ Wih, const float* __restrict__ bih,
    const float* __restrict__ Whh, const float* __restrict__ bhh,
    const float* __restrict__ lng, const float* __restrict__ lnb,
    const float* __restrict__ Whd, const float* __restrict__ bhp,
    float* __restrict__ out)
{
  const int b = blockIdx.x;
  const int tid = threadIdx.x;
  const int lane = tid & 63;
  const int wv = tid >> 6;
  const int jj = lane & 15;
  const int ks = lane >> 4;
  const int j = (wv << 4) + jj;     // 0..127
  const int k016 = ks << 4;         // 16-wide slice base (F=64)
  const int k032 = ks << 5;         // 32-wide slice base (K=128)

  __shared__ int   act_lds[Ll];     // 4 KB
  __shared__ __align__(16) float x_lds[Ff];
  __shared__ __align__(16) float xe_lds[Ee];
  __shared__ __align__(16) float gi_lds[3 * Hh];
  __shared__ __align__(16) float h_lds[Hh];
  __shared__ __align__(16) float u_lds[Hh];
  __shared__ float red_lds[8];

  // ---- phase 0: act[t] = any_b mask[b][t] (same result in every WG) ----
  for (int t = tid; t < Ll; t += 512) {
    int a = 0;
    for (int bb = 0; bb < Bb; ++bb) a |= mask[(size_t)bb * Ll + t];
    act_lds[t] = a;
  }

  // ---- weights to registers ----
  float wx[16];
#pragma unroll
  for (int c = 0; c < 16; ++c) wx[c] = Wx[(size_t)j * Ff + k016 + c];

  float w1r[32], w2r[32];
#pragma unroll
  for (int ii = 0; ii < 8; ++ii) {
    const int slot = (ii + 2 * ks) & 7;      // bank-staggered rotation
    const int kb = k032 + 4 * slot;
    float4 a4;
    a4 = *(const float4*)&W1[(size_t)j * Hh + kb];
    w1r[4*ii+0]=a4.x; w1r[4*ii+1]=a4.y; w1r[4*ii+2]=a4.z; w1r[4*ii+3]=a4.w;
    a4 = *(const float4*)&W2[(size_t)j * Hh + kb];
    w2r[4*ii+0]=a4.x; w2r[4*ii+1]=a4.y; w2r[4*ii+2]=a4.z; w2r[4*ii+3]=a4.w;
  }

  // W_ih, W_hh packed f16 (f32 accumulate at use)
  __half2 wih[3][16], whhp[3][16];
#pragma unroll
  for (int G = 0; G < 3; ++G) {
#pragma unroll
    for (int ii = 0; ii < 8; ++ii) {
      const int slot = (ii + 2 * ks) & 7;
      const int kb = k032 + 4 * slot;
      float4 a4;
      a4 = *(const float4*)&Wih[((size_t)(G * Hh + j)) * Ee + kb];
      wih[G][2*ii+0] = __halves2half2(__float2half_rn(a4.x), __float2half_rn(a4.y));
      wih[G][2*ii+1] = __halves2half2(__float2half_rn(a4.z), __float2half_rn(a4.w));
      a4 = *(const float4*)&Whh[((size_t)(G * Hh + j)) * Hh + kb];
      whhp[G][2*ii+0] = __halves2half2(__float2half_rn(a4.x), __float2half_rn(a4.y));
      whhp[G][2*ii+1] = __halves2half2(__float2half_rn(a4.z), __float2half_rn(a4.w));
    }
  }
  const float bxj = bx[j];
  const float b1j = b1[j], b2j = b2[j];
  const float bir = bih[j], biz = bih[Hh + j], bin_ = bih[2*Hh + j];
  const float bhr = bhh[j], bhz = bhh[Hh + j], bhn = bhh[2*Hh + j];

  // ---- LN/head constants: c1 = sum(g*wh), c0 = sum(b*wh) + bh ----
  float gw = 0.0f;
  {
    float t1 = 0.0f, t0 = 0.0f;
    if (tid < Hh) {
      const float g = lng[tid], bbv = lnb[tid], wh = Whd[tid];
      gw = g * wh;
      t1 = gw;
      t0 = bbv * wh;
    }
    t1 = redu64(t1); t0 = redu64(t0);
    if (tid < Hh && lane == 0) { red_lds[wv*2+0] = t1; red_lds[wv*2+1] = t0; }
    if (tid < Hh) h_lds[tid] = 0.0f;
  }
  __syncthreads();
  const float c1 = red_lds[0] + red_lds[2];
  const float c0 = red_lds[1] + red_lds[3] + bhp[0];

  float hreg = 0.0f;                 // ks==0 lanes: h[j]
  float acc = 0.0f, cnt = 0.0f;      // tid==0: masked logit sum / count

#pragma unroll 1
  for (int t = 0; t < Ll; ++t) {
    if (tid < 16)
      *(float4*)&x_lds[4*tid] = *(const float4*)(x + ((size_t)b * Ll + t) * Ff + 4*tid);
    const float dtv = dtp[(size_t)b * Ll + t];
    const int m = mask[(size_t)b * Ll + t];
    const int act = act_lds[t];
    const float stepv = dtv * (float)m * 0.25f;
    __syncthreads();                                 // (b) x ready

    // ---- xe = relu(x @ Wx^T + bx) ----
    float p = 0.0f;
#pragma unroll
    for (int c = 0; c < 16; ++c) p = fmaf(wx[c], x_lds[k016 + c], p);
    p = redu4(p);
    if (ks == 0) xe_lds[j] = fmaxf(p + bxj, 0.0f);
    __syncthreads();                                 // (c) xe ready

    // ---- gi = xe @ W_ih^T + b_ih (r,z,n) ----
    float gr = 0.0f, gz = 0.0f, gn = 0.0f;
#pragma unroll
    for (int ii = 0; ii < 8; ++ii) {
      const int slot = (ii + 2 * ks) & 7;
      const float4 ev = *(const float4*)&xe_lds[k032 + 4*slot];
      float2 lo, hi;
      lo = __half22float2(wih[0][2*ii]); hi = __half22float2(wih[0][2*ii+1]);
      gr = fmaf(lo.x, ev.x, gr); gr = fmaf(lo.y, ev.y, gr);
      gr = fmaf(hi.x, ev.z, gr); gr = fmaf(hi.y, ev.w, gr);
      lo = __half22float2(wih[1][2*ii]); hi = __half22float2(wih[1][2*ii+1]);
      gz = fmaf(lo.x, ev.x, gz); gz = fmaf(lo.y, ev.y, gz);
      gz = fmaf(hi.x, ev.z, gz); gz = fmaf(hi.y, ev.w, gz);
      lo = __half22float2(wih[2][2*ii]); hi = __half22float2(wih[2][2*ii+1]);
      gn = fmaf(lo.x, ev.x, gn); gn = fmaf(lo.y, ev.y, gn);
      gn = fmaf(hi.x, ev.z, gn); gn = fmaf(hi.y, ev.w, gn);
    }
    gr = redu4(gr); gz = redu4(gz); gn = redu4(gn);
    if (ks == 0) {
      gi_lds[j]        = gr + bir;
      gi_lds[Hh + j]   = gz + biz;
      gi_lds[2*Hh + j] = gn + bin_;
    }
    // no barrier: gi_lds first consumed after the ODE barriers below

    // ---- ODE: 4 Euler substeps ----
#pragma unroll 1
    for (int s = 0; s < 4; ++s) {
      float pa = 0.0f;
#pragma unroll
      for (int ii = 0; ii < 8; ++ii) {
        const int slot = (ii + 2 * ks) & 7;
        const float4 hv = *(const float4*)&h_lds[k032 + 4*slot];
        pa = fmaf(w1r[4*ii+0], hv.x, pa); pa = fmaf(w1r[4*ii+1], hv.y, pa);
        pa = fmaf(w1r[4*ii+2], hv.z, pa); pa = fmaf(w1r[4*ii+3], hv.w, pa);
      }
      pa = redu4(pa);
      if (ks == 0) u_lds[j] = fast_tanh(pa + b1j);
      __syncthreads();
      float qa = 0.0f;
#pragma unroll
      for (int ii = 0; ii < 8; ++ii) {
        const int slot = (ii + 2 * ks) & 7;
        const float4 uv = *(const float4*)&u_lds[k032 + 4*slot];
        qa = fmaf(w2r[4*ii+0], uv.x, qa); qa = fmaf(w2r[4*ii+1], uv.y, qa);
        qa = fmaf(w2r[4*ii+2], uv.z, qa); qa = fmaf(w2r[4*ii+3], uv.w, qa);
      }
      qa = redu4(qa);
      if (ks == 0) { hreg = fmaf(stepv, qa + b2j, hreg); h_lds[j] = hreg; }
      __syncthreads();
    }

    // ---- GRU gates: gh = h @ W_hh^T ----
    float pr = 0.0f, pz = 0.0f, pn = 0.0f;
#pragma unroll
    for (int ii = 0; ii < 8; ++ii) {
      const int slot = (ii + 2 * ks) & 7;
      const float4 hv = *(const float4*)&h_lds[k032 + 4*slot];
      float2 lo, hi;
      lo = __half22float2(whhp[0][2*ii]); hi = __half22float2(whhp[0][2*ii+1]);
      pr = fmaf(lo.x, hv.x, pr); pr = fmaf(lo.y, hv.y, pr);
      pr = fmaf(hi.x, hv.z, pr); pr = fmaf(hi.y, hv.w, pr);
      lo = __half22float2(whhp[1][2*ii]); hi = __half22float2(whhp[1][2*ii+1]);
      pz = fmaf(lo.x, hv.x, pz); pz = fmaf(lo.y, hv.y, pz);
      pz = fmaf(hi.x, hv.z, pz); pz = fmaf(hi.y, hv.w, pz);
      lo = __half22float2(whhp[2][2*ii]); hi = __half22float2(whhp[2][2*ii+1]);
      pn = fmaf(lo.x, hv.x, pn); pn = fmaf(lo.y, hv.y, pn);
      pn = fmaf(hi.x, hv.z, pn); pn = fmaf(hi.y, hv.w, pn);
    }
    pr = redu4(pr); pz = redu4(pz); pn = redu4(pn);
    __syncthreads();                                 // (e) all done reading h_lds

    if (ks == 0) {
      const float r = fast_sigmoid(gi_lds[j] + pr + bhr);
      const float z = fast_sigmoid(gi_lds[Hh + j] + pz + bhz);
      const float n = fast_tanh(gi_lds[2*Hh + j] + r * (pn + bhn));
      const float hg = (1.0f - z) * n + z * hreg;
      if (act) hreg = hg;                            // h_new = active ? hg : h
      h_lds[j] = hreg;
    }
    __syncthreads();                                 // (f) h_new visible

    // ---- LN + head contribution (inline) ----
    float s1 = 0.0f, s2 = 0.0f, sd = 0.0f;
    if (tid < Hh) {
      const float hv = h_lds[tid];
      s1 = hv; s2 = hv * hv; sd = hv * gw;
    }
    s1 = redu64(s1); s2 = redu64(s2); sd = redu64(sd);
    if (tid < Hh && lane == 0) {
      red_lds[wv*3+0] = s1; red_lds[wv*3+1] = s2; red_lds[wv*3+2] = sd;
    }
    __syncthreads();                                 // (g) partials visible
    if (tid == 0 && m) {
      const float S1 = red_lds[0] + red_lds[3];
      const float S2 = red_lds[1] + red_lds[4];
      const float SD = red_lds[2] + red_lds[5];
      const float mu = S1 * (1.0f / 128.0f);
      const float var = S2 * (1.0f / 128.0f) - mu * mu;
      const float rstd = rsqrtf(var + 1e-5f);
      acc += rstd * (SD - mu * c1) + c0;
      cnt += 1.0f;
    }
  }

  if (tid == 0) out[b] = acc / fmaxf(cnt, 1.0f);   // FLOAT32 output
}

// ---------------- host ----------------
extern "C" void kernel_launch(void* const* d_in, const int* in_sizes, int n_in,
                              void* d_out, int out_size, void* d_ws, size_t ws_size,
                              hipStream_t stream) {
  const float* x    = (const float*)d_in[0];
  const float* dt   = (const float*)d_in[1];
  const int*   mask = (const int*)d_in[2];
  const float* Wx   = (const float*)d_in[3];
  const float* bx   = (const float*)d_in[4];
  const float* W1   = (const float*)d_in[5];
  const float* b1   = (const float*)d_in[6];
  const float* W2   = (const float*)d_in[7];
  const float* b2   = (const float*)d_in[8];
  const float* Wih  = (const float*)d_in[9];
  const float* bih  = (const float*)d_in[10];
  const float* Whh  = (const float*)d_in[11];
  const float* bhh  = (const float*)d_in[12];
  const float* lng  = (const float*)d_in[13];
  const float* lnb  = (const float*)d_in[14];
  const float* Wh   = (const float*)d_in[15];
  const float* bh   = (const float*)d_in[16];
  float* out = (float*)d_out;   // reference output dtype is float32

  k_fused<<<dim3(Bb), dim3(512), 0, stream>>>(
      x, dt, mask, Wx, bx, W1, b1, W2, b2, Wih, bih, Whh, bhh,
      lng, lnb, Wh, bh, out);
}